// Round 9
// baseline (194.844 us; speedup 1.0000x reference)
//
#include <hip/hip_runtime.h>
#include <hip/hip_bf16.h>
#include <math.h>

#define B_  256
#define K_  256
#define C_  128
#define KG_ 64
#define O3_ 117
#define OD_ 183

#define A_OFF    0
#define W_OFF    32768
// scratch overlapped into the A region (A dead at those points):
#define RED_OFF  0       // redf4 (4KB)
#define SCSH_OFF 4096    // sc|sh 256 floats (1KB)

typedef unsigned int  u32;
typedef unsigned short u16;
typedef __bf16 bf16_t;
typedef bf16_t bf16x8 __attribute__((ext_vector_type(8)));
typedef float  f32x4  __attribute__((ext_vector_type(4)));

__device__ __forceinline__ float bflo(u32 u){ return __uint_as_float(u << 16); }
__device__ __forceinline__ float bfhi(u32 u){ return __uint_as_float(u & 0xffff0000u); }
__device__ __forceinline__ u16 f2bf(float f){
    __hip_bfloat16 h = __float2bfloat16(f);
    return __builtin_bit_cast(u16, h);
}
// LDS row swizzle: rows 256B; XOR byte-bits 4-6 with (row>>1)&7.
__device__ __forceinline__ int swz(int row, int byteInRow){
    return row * 256 + (byteInRow ^ (((row >> 1) & 7) << 4));
}

// ---------------------------------------------------------------------------
// stage A (layer1): fp32 [c][k] global -> bf16 [pt][c] swizzled LDS  [R5-proven]
// ---------------------------------------------------------------------------
__device__ __forceinline__ void stageA_f32(char* smem, const float* __restrict__ src,
                                           int bb, int k0, int t)
{
    const int q  = t & 31;
    const int cb = t >> 5;
#pragma unroll
    for (int j = 0; j < 4; ++j) {
        int cq = cb + j * 8;
        float4 r0 = *(const float4*)(src + ((size_t)(bb*C_ + cq*4 + 0))*K_ + k0 + q*4);
        float4 r1 = *(const float4*)(src + ((size_t)(bb*C_ + cq*4 + 1))*K_ + k0 + q*4);
        float4 r2 = *(const float4*)(src + ((size_t)(bb*C_ + cq*4 + 2))*K_ + k0 + q*4);
        float4 r3 = *(const float4*)(src + ((size_t)(bb*C_ + cq*4 + 3))*K_ + k0 + q*4);
        const float* p0 = (const float*)&r0;
        const float* p1 = (const float*)&r1;
        const float* p2 = (const float*)&r2;
        const float* p3 = (const float*)&r3;
#pragma unroll
        for (int p = 0; p < 4; ++p) {
            int row = q * 4 + p;
            uint2 uv;
            uv.x = (u32)f2bf(p0[p]) | ((u32)f2bf(p1[p]) << 16);
            uv.y = (u32)f2bf(p2[p]) | ((u32)f2bf(p3[p]) << 16);
            *(uint2*)(smem + A_OFF + swz(row, cq * 8)) = uv;
        }
    }
}

// ---------------------------------------------------------------------------
// stage W: fp32 [o][ldw] global -> bf16 [o][c] swizzled LDS (zero-pad rows)
// (same LDS addressing as R5's proven stage_w128; adds inline fp32->bf16)
// ---------------------------------------------------------------------------
__device__ __forceinline__ void stageW_f32(char* smem, const float* __restrict__ W,
                                           int ldw, int colOff, int rowLimit, int t)
{
    int c8 = (t & 15) * 8;
#pragma unroll
    for (int rr = 0; rr < 8; ++rr) {
        int row = (t >> 4) + rr * 16;
        uint4 q2 = {0, 0, 0, 0};
        if (row < rowLimit) {
            float4 v0 = *(const float4*)(W + (size_t)row * ldw + colOff + c8);
            float4 v1 = *(const float4*)(W + (size_t)row * ldw + colOff + c8 + 4);
            q2.x = (u32)f2bf(v0.x) | ((u32)f2bf(v0.y) << 16);
            q2.y = (u32)f2bf(v0.z) | ((u32)f2bf(v0.w) << 16);
            q2.z = (u32)f2bf(v1.x) | ((u32)f2bf(v1.y) << 16);
            q2.w = (u32)f2bf(v1.z) | ((u32)f2bf(v1.w) << 16);
        }
        *(uint4*)(smem + W_OFF + swz(row, c8 * 2)) = q2;
    }
}

// ---------------------------------------------------------------------------
// MFMA compute: acc += A[128x128] * W^T[128x128] over K=128   [R5-proven]
// ---------------------------------------------------------------------------
__device__ __forceinline__ void compute_tile(const char* smem, f32x4 acc[2][8],
                                             int w, int lr, int lg)
{
#pragma unroll
    for (int ks = 0; ks < 4; ++ks) {
        bf16x8 a[2], bfr[8];
#pragma unroll
        for (int m = 0; m < 2; ++m) {
            int row = w * 32 + m * 16 + lr;
            a[m] = *(const bf16x8*)(smem + A_OFF + swz(row, ks * 64 + lg * 16));
        }
#pragma unroll
        for (int n = 0; n < 8; ++n) {
            int row = n * 16 + lr;
            bfr[n] = *(const bf16x8*)(smem + W_OFF + swz(row, ks * 64 + lg * 16));
        }
#pragma unroll
        for (int m = 0; m < 2; ++m)
#pragma unroll
            for (int n = 0; n < 8; ++n)
                acc[m][n] = __builtin_amdgcn_mfma_f32_16x16x32_bf16(a[m], bfr[n], acc[m][n], 0, 0, 0);
    }
}

// ---------------------------------------------------------------------------
// bias + pre-BN act -> LDS [c][pt] image (264B stride) + stats partials ->
// coalesced blocked store [tb][128c][128pt] + per-tile partials  [R5-proven]
// ---------------------------------------------------------------------------
__device__ __forceinline__ void epilogue_store(char* smem, const f32x4 acc[2][8],
                                               const float* __restrict__ bias,
                                               u16* __restrict__ outp, float* __restrict__ part,
                                               int tb, int t, int w, int lr, int lg)
{
    float* SP = (float*)(smem + 40960);   // [16][128]
    float* SQ = (float*)(smem + 49152);   // [16][128]
#pragma unroll
    for (int n = 0; n < 8; ++n) {
        int o = n * 16 + lr;
        float bvn = bias[o];
        float s = 0.f, q = 0.f;
#pragma unroll
        for (int m = 0; m < 2; ++m) {
            float v0 = acc[m][n][0] + bvn;
            float v1 = acc[m][n][1] + bvn;
            float v2 = acc[m][n][2] + bvn;
            float v3 = acc[m][n][3] + bvn;
            s += (v0 + v1) + (v2 + v3);
            q = fmaf(v0, v0, q); q = fmaf(v1, v1, q);
            q = fmaf(v2, v2, q); q = fmaf(v3, v3, q);
            uint2 pk;
            pk.x = (u32)f2bf(v0) | ((u32)f2bf(v1) << 16);
            pk.y = (u32)f2bf(v2) | ((u32)f2bf(v3) << 16);
            *(uint2*)(smem + o * 264 + (w * 32 + m * 16 + lg * 4) * 2) = pk;
        }
        SP[(w * 4 + lg) * 128 + o] = s;
        SQ[(w * 4 + lg) * 128 + o] = q;
    }
    __syncthreads();
    u16* dst = outp + (size_t)tb * 16384;
#pragma unroll
    for (int j = 0; j < 8; ++j) {
        int i = t + j * 256;
        int c = i >> 4, col = i & 15;
        uint4 v = *(const uint4*)(smem + c * 264 + col * 16);
        *(uint4*)(dst + c * 128 + col * 8) = v;
    }
    if (t < 128) {
        float s = 0.f, q = 0.f;
#pragma unroll
        for (int i = 0; i < 16; ++i) { s += SP[i * 128 + t]; q += SQ[i * 128 + t]; }
        part[tb * 256 + t] = s;
        part[tb * 256 + 128 + t] = q;
    }
}

// ---------------------------------------------------------------------------
// per-block: reduce 512 tile-partials -> sc/sh in LDS @ SCSH_OFF
// ---------------------------------------------------------------------------
__device__ __forceinline__ void reduce_finalize(char* smem, const float* __restrict__ part,
                                                const float* __restrict__ g,
                                                const float* __restrict__ be, int t)
{
    float4* redf4 = (float4*)(smem + RED_OFF);
    const int q4 = t & 63, slice = t >> 6;
    float4 v = {0.f, 0.f, 0.f, 0.f};
    const float* base = part + q4 * 4;
#pragma unroll 8
    for (int i = 0; i < 128; ++i) {
        float4 p = *(const float4*)(base + (size_t)(slice * 128 + i) * 256);
        v.x += p.x; v.y += p.y; v.z += p.z; v.w += p.w;
    }
    redf4[slice * 64 + q4] = v;
    __syncthreads();
    float* scsh = (float*)(smem + SCSH_OFF);
    if (t < 64) {
        float4 a = redf4[t], b = redf4[64 + t], c = redf4[128 + t], d = redf4[192 + t];
        float4 s;
        s.x = (a.x + b.x) + (c.x + d.x);
        s.y = (a.y + b.y) + (c.y + d.y);
        s.z = (a.z + b.z) + (c.z + d.z);
        s.w = (a.w + b.w) + (c.w + d.w);
        *(float4*)(scsh + t * 4) = s;
    }
    __syncthreads();
    if (t < 128) {
        const float inv = 1.0f / 65536.0f;
        float mean = scsh[t] * inv;
        float var  = scsh[128 + t] * inv - mean * mean;
        float sv   = g[t] * rsqrtf(var + 1e-5f);
        float shv  = be[t] - mean * sv;
        scsh[t] = sv;
        scsh[128 + t] = shv;
    }
}

// load this thread's 16 BN coefs from LDS scsh into registers
__device__ __forceinline__ void load_coefs(const char* smem, float ss[2][4], float tt[2][4], int t)
{
    const float* scsh = (const float*)(smem + SCSH_OFF);
    const int cb = t >> 4;
#pragma unroll
    for (int j = 0; j < 2; ++j) {
        int c0 = j * 64 + cb * 4;
#pragma unroll
        for (int i2 = 0; i2 < 4; ++i2) {
            ss[j][i2] = scsh[c0 + i2];
            tt[j][i2] = scsh[128 + c0 + i2];
        }
    }
}

// ---------------------------------------------------------------------------
// BN+ReLU restage: global blocked act [c][pt] -> A [pt][c] swizzled bf16
// (identical math/addressing to R5's proven stage_bn; coefs from registers)
// ---------------------------------------------------------------------------
__device__ __forceinline__ void stage_bn_reg(char* smem, const u16* __restrict__ tile,
                                             const float ss[2][4], const float tt[2][4], int t)
{
    const int q = t & 15, cb = t >> 4;
#pragma unroll
    for (int j = 0; j < 2; ++j) {
        int c0 = j * 64 + cb * 4;
        u32 R[4][4];
#pragma unroll
        for (int i2 = 0; i2 < 4; ++i2) {
            uint4 v = *(const uint4*)(tile + (size_t)(c0 + i2) * 128 + q * 8);
            R[i2][0] = v.x; R[i2][1] = v.y; R[i2][2] = v.z; R[i2][3] = v.w;
        }
#pragma unroll
        for (int p = 0; p < 8; ++p) {
            int wi = p >> 1;
            float f0, f1, f2, f3;
            if (p & 1) {
                f0 = bfhi(R[0][wi]); f1 = bfhi(R[1][wi]);
                f2 = bfhi(R[2][wi]); f3 = bfhi(R[3][wi]);
            } else {
                f0 = bflo(R[0][wi]); f1 = bflo(R[1][wi]);
                f2 = bflo(R[2][wi]); f3 = bflo(R[3][wi]);
            }
            f0 = fmaxf(0.f, fmaf(f0, ss[j][0], tt[j][0]));
            f1 = fmaxf(0.f, fmaf(f1, ss[j][1], tt[j][1]));
            f2 = fmaxf(0.f, fmaf(f2, ss[j][2], tt[j][2]));
            f3 = fmaxf(0.f, fmaf(f3, ss[j][3], tt[j][3]));
            uint2 pk;
            pk.x = (u32)f2bf(f0) | ((u32)f2bf(f1) << 16);
            pk.y = (u32)f2bf(f2) | ((u32)f2bf(f3) << 16);
            *(uint2*)(smem + A_OFF + swz(q * 8 + p, c0 * 2)) = pk;
        }
    }
}

// ---------------------------------------------------------------------------
// K1: blocks 0..511 layer-1 GEMM tiles; 512..767 objness; 768..1023 getindex
// ---------------------------------------------------------------------------
__global__ __launch_bounds__(256, 2) void k1_kernel(const float* __restrict__ fa,
                                                    const float* __restrict__ fb,
                                                    const float* __restrict__ W1,
                                                    const float* __restrict__ b1,
                                                    const float* __restrict__ xyz,
                                                    const float* __restrict__ gtc,
                                                    const int*   __restrict__ pred,
                                                    u16* __restrict__ act1,
                                                    float* __restrict__ part1,
                                                    float* __restrict__ label,
                                                    float* __restrict__ idxo,
                                                    float* __restrict__ sum1)
{
    __shared__ __align__(16) char smem[65536];
    const int blk = blockIdx.x, t = threadIdx.x;

    if (blk < 512) {
        const int pb = blk;
        const int bb = pb >> 1;
        const int k0 = (pb & 1) << 7;
        const int w  = t >> 6, l = t & 63;
        const int lr = l & 15, lg = l >> 4;

        f32x4 acc[2][8] = {};
        stageA_f32(smem, fa, bb, k0, t);
        stageW_f32(smem, W1, 256, 0, 128, t);
        __syncthreads();
        compute_tile(smem, acc, w, lr, lg);
        __syncthreads();
        stageA_f32(smem, fb, bb, k0, t);
        stageW_f32(smem, W1, 256, 128, 128, t);
        __syncthreads();
        compute_tile(smem, acc, w, lr, lg);
        __syncthreads();
        epilogue_store(smem, acc, b1, act1, part1, pb, t, w, lr, lg);
    } else if (blk < 768) {
        float* gg = (float*)smem;
        const int b = blk - 512;
        if (t < KG_ * 3) gg[t] = gtc[(size_t)b * KG_ * 3 + t];
        __syncthreads();
        const size_t pidx = (size_t)(b * K_ + t);
        float x = xyz[pidx * 3 + 0];
        float y = xyz[pidx * 3 + 1];
        float z = xyz[pidx * 3 + 2];
        float dmin = 1e30f;
#pragma unroll 8
        for (int j = 0; j < KG_; ++j) {
            float dx = x - gg[j * 3 + 0];
            float dy = y - gg[j * 3 + 1];
            float dz = z - gg[j * 3 + 2];
            float d  = dx * dx + dy * dy + dz * dz;
            dmin = fminf(dmin, d);
        }
        float e = sqrtf(dmin + 1e-6f);
        label[pidx] = (e < 0.3f) ? 1.0f : 0.0f;
    } else {
        int* sd = (int*)smem;
        const int b = blk - 768;
        const int p = (pred[b * K_ + t] == 1) ? 1 : 0;
        sd[t] = p;
        __syncthreads();
        for (int off = 1; off < K_; off <<= 1) {
            int v = (t >= off) ? sd[t - off] : 0;
            __syncthreads();
            sd[t] += v;
            __syncthreads();
        }
        const int incl = sd[t];
        const int num  = sd[K_ - 1];
        if (t >= num) idxo[b * K_ + t] = (float)t;
        if (p)        idxo[b * K_ + (incl - p)] = (float)t;
        if (t == 0)   sum1[b] = (float)num;
    }
}

// ---------------------------------------------------------------------------
// K2: per-block BN1 finalize + BN+ReLU stage + layer-2 GEMM -> act2 + part2
// ---------------------------------------------------------------------------
__global__ __launch_bounds__(256, 2) void k2_kernel(const u16* __restrict__ act1,
                                                    const float* __restrict__ part1,
                                                    const float* __restrict__ g1,
                                                    const float* __restrict__ be1,
                                                    const float* __restrict__ W2,
                                                    const float* __restrict__ b2,
                                                    u16* __restrict__ act2,
                                                    float* __restrict__ part2)
{
    __shared__ __align__(16) char smem[65536];
    const int pb = blockIdx.x, t = threadIdx.x;
    const int w  = t >> 6, l = t & 63;
    const int lr = l & 15, lg = l >> 4;

    reduce_finalize(smem, part1, g1, be1, t);
    __syncthreads();
    float ss[2][4], tt[2][4];
    load_coefs(smem, ss, tt, t);
    __syncthreads();

    f32x4 acc[2][8] = {};
    stage_bn_reg(smem, act1 + (size_t)pb * 16384, ss, tt, t);
    stageW_f32(smem, W2, 128, 0, 128, t);
    __syncthreads();
    compute_tile(smem, acc, w, lr, lg);
    __syncthreads();
    epilogue_store(smem, acc, b2, act2, part2, pb, t, w, lr, lg);
}

// ---------------------------------------------------------------------------
// K3: per-block BN2 finalize + BN+ReLU stage + layer-3 GEMM + transform out
// ---------------------------------------------------------------------------
__global__ __launch_bounds__(256, 2) void k3_kernel(const u16* __restrict__ act2,
                                                    const float* __restrict__ part2,
                                                    const float* __restrict__ g2,
                                                    const float* __restrict__ be2,
                                                    const float* __restrict__ W3,
                                                    const float* __restrict__ b3,
                                                    const float* __restrict__ xyz,
                                                    const float* __restrict__ msize,
                                                    float* __restrict__ out)
{
    __shared__ __align__(16) char smem[65536];
    const int pb = blockIdx.x, t = threadIdx.x;
    const int pt0 = pb * 128;
    const int w  = t >> 6, l = t & 63;
    const int lr = l & 15, lg = l >> 4;

    reduce_finalize(smem, part2, g2, be2, t);
    __syncthreads();
    float ss[2][4], tt[2][4];
    load_coefs(smem, ss, tt, t);
    __syncthreads();

    f32x4 acc[2][8] = {};
    stage_bn_reg(smem, act2 + (size_t)pb * 16384, ss, tt, t);
    stageW_f32(smem, W3, 128, 0, O3_, t);
    __syncthreads();
    compute_tile(smem, acc, w, lr, lg);

    const float PI12 = 0.26179938779914946f;
    for (int s = 0; s < 2; ++s) {
        __syncthreads();
        if ((w >> 1) == s) {
            float* Of = (float*)smem + (w & 1) * (32 * 184);
#pragma unroll
            for (int n = 0; n < 8; ++n) {
                int o = n * 16 + lr;
                if (o < O3_) {
                    float bvn = b3[o];
                    float msv = (o >= 45 && o < 99) ? msize[o - 45] : 0.f;
#pragma unroll
                    for (int m = 0; m < 2; ++m)
#pragma unroll
                        for (int r = 0; r < 4; ++r) {
                            int pl = m * 16 + lg * 4 + r;
                            float v = acc[m][n][r] + bvn;
                            float* row = Of + pl * 184;
                            if (o < 3) {
                                int gp = pt0 + w * 32 + pl;
                                row[o] = v + xyz[(size_t)gp * 3 + o];
                            } else if (o < 15) {
                                row[o] = v;
                            } else if (o < 27) {
                                row[o] = v; row[o + 12] = v * PI12;
                            } else if (o < 45) {
                                row[o + 12] = v;
                            } else if (o < 99) {
                                row[o + 12] = v; row[o + 66] = v * msv;
                            } else {
                                row[o + 66] = v;
                            }
                        }
                }
            }
        }
        __syncthreads();
        float* Ob = out + (size_t)(pt0 + s * 64) * OD_;
        const float* Sf = (const float*)smem;
        for (int i = t; i < 64 * OD_; i += 256) {
            int pl  = (int)(((u32)i * 91680u) >> 24);   // i / 183
            int col = i - pl * 183;
            Ob[i] = Sf[(pl >> 5) * (32 * 184) + (pl & 31) * 184 + col];
        }
    }
}

// ---------------------------------------------------------------------------
extern "C" void kernel_launch(void* const* d_in, const int* in_sizes, int n_in,
                              void* d_out, int out_size, void* d_ws, size_t ws_size,
                              hipStream_t stream)
{
    const float* xyz      = (const float*)d_in[0];
    const float* features = (const float*)d_in[1];
    const float* rn       = (const float*)d_in[2];
    const float* gtc      = (const float*)d_in[3];
    const int*   pred     = (const int*)d_in[4];
    const float* W1  = (const float*)d_in[5];
    const float* b1  = (const float*)d_in[6];
    const float* g1  = (const float*)d_in[7];
    const float* be1 = (const float*)d_in[8];
    const float* W2  = (const float*)d_in[9];
    const float* b2  = (const float*)d_in[10];
    const float* g2  = (const float*)d_in[11];
    const float* be2 = (const float*)d_in[12];
    const float* W3  = (const float*)d_in[13];
    const float* b3  = (const float*)d_in[14];
    const float* ms  = (const float*)d_in[15];

    float* out = (float*)d_out;
    const size_t OFF_IDX = (size_t)B_ * K_ * OD_;
    const size_t OFF_SUM = OFF_IDX + (size_t)B_ * K_;
    const size_t OFF_LAB = OFF_SUM + B_;

    char* ws = (char*)d_ws;
    u16*  act1  = (u16*)ws;                       // 16 MB blocked [512][128][128]
    u16*  act2  = (u16*)(ws + 16777216);          // 16 MB
    float* part1 = (float*)(ws + 33554432);       // 512 KB
    float* part2 = (float*)(ws + 34078720);       // 512 KB

    k1_kernel<<<1024, 256, 0, stream>>>(features, rn, W1, b1, xyz, gtc, pred,
                                        act1, part1,
                                        out + OFF_LAB, out + OFF_IDX, out + OFF_SUM);
    k2_kernel<<<512, 256, 0, stream>>>(act1, part1, g1, be1, W2, b2, act2, part2);
    k3_kernel<<<512, 256, 0, stream>>>(act2, part2, g2, be2, W3, b3, xyz, ms, out);
}